// Round 1
// baseline (547.335 us; speedup 1.0000x reference)
//
#include <hip/hip_runtime.h>
#include <hip/hip_bf16.h>

// Problem constants
#define HH   8
#define Bb   8
#define Kk   64
#define Nn   16384
#define DQd  256
#define NCc  8          // n-chunks per (b,h)
#define NCHUNK 2048     // Nn / NCc
#define EPSf 1e-5f

typedef __bf16 bf16_t;
typedef __bf16 bf16x8 __attribute__((ext_vector_type(8)));
typedef __bf16 bf16x4 __attribute__((ext_vector_type(4)));
typedef float  f32x4  __attribute__((ext_vector_type(4)));

#define MFMA(a, b, c) __builtin_amdgcn_mfma_f32_16x16x32_bf16((a), (b), (c), 0, 0, 0)

// ---------------------------------------------------------------------------
// Kernel 1: LN1 + q = norm @ Wq_h (scaled) + q_tilde = q @ Wk_h^T  -> bf16
// grid (B*H) blocks, 256 threads. Wave w owns q-rows [w*16, w*16+16).
// ---------------------------------------------------------------------------
__global__ __launch_bounds__(256) void k1_qt(
    const float* __restrict__ slots, const float* __restrict__ g1,
    const float* __restrict__ bb1, const float* __restrict__ Wq,
    const float* __restrict__ Wk, bf16_t* __restrict__ qt)
{
    __shared__ alignas(16) bf16_t nrow[64][264];   // LN(slots) rows, bf16, padded
    __shared__ alignas(16) bf16_t wqT[64][264];    // wqT[d][i] = Wq[i][h*64+d]
    __shared__ alignas(16) bf16_t qb[64][72];      // q[k][d] (scaled by 1/8)
    __shared__ alignas(16) bf16_t wkT[256][72];    // wkT[c][d] = Wk[c][h*64+d]

    const int b = blockIdx.x >> 3, h = blockIdx.x & 7;
    const int t = threadIdx.x;
    const int w = t >> 6, lane = t & 63;
    const int l15 = lane & 15, quad = lane >> 4;

    // ---- LayerNorm of 16 rows per wave (wave-local reduction over 256) ----
    {
        float4 gv = *(const float4*)&g1[lane * 4];
        float4 bv = *(const float4*)&bb1[lane * 4];
        for (int i = 0; i < 16; ++i) {
            int row = w * 16 + i;
            float4 x = *(const float4*)&slots[((size_t)b * Kk + row) * DQd + lane * 4];
            float s = x.x + x.y + x.z + x.w;
            for (int m = 1; m < 64; m <<= 1) s += __shfl_xor(s, m, 64);
            float mean = s * (1.0f / 256.0f);
            float dx = x.x - mean, dy = x.y - mean, dz = x.z - mean, dw = x.w - mean;
            float v2 = dx * dx + dy * dy + dz * dz + dw * dw;
            for (int m = 1; m < 64; m <<= 1) v2 += __shfl_xor(v2, m, 64);
            float rs = rsqrtf(v2 * (1.0f / 256.0f) + EPSf);
            bf16x4 o;
            o[0] = (bf16_t)(dx * rs * gv.x + bv.x);
            o[1] = (bf16_t)(dy * rs * gv.y + bv.y);
            o[2] = (bf16_t)(dz * rs * gv.z + bv.z);
            o[3] = (bf16_t)(dw * rs * gv.w + bv.w);
            *(bf16x4*)&nrow[row][lane * 4] = o;
        }
    }
    // ---- stage weight slices (head h) into LDS as bf16 ----
    {
        int d = t & 63, r4 = t >> 6;
        for (int p = 0; p < 64; ++p) {
            int i = r4 + p * 4;     // 0..255
            wqT[d & 63][i & 255] = (i < 64) ? (bf16_t)Wq[(size_t)i * 512 + h * 64 + d] : (bf16_t)0.0f;
            wkT[i][d] = (bf16_t)Wk[(size_t)i * 512 + h * 64 + d];
        }
        // wqT only has 64 i-columns... redo properly below
    }
    __syncthreads();
    // fix wqT staging (i runs 0..255 for Wq rows; wqT is [d][i] with i=0..255)
    // NOTE: wqT dims are [64][264]: row=d (64), col=i (256). Staged here:
    {
        int d = t & 63, r4 = t >> 6;
        for (int p = 0; p < 64; ++p) {
            int i = r4 + p * 4;     // 0..255
            wqT[d][i] = (bf16_t)Wq[(size_t)i * 512 + h * 64 + d];
        }
    }
    __syncthreads();

    // ---- GEMM1: q[64k x 64d] = nrow[64k x 256i] @ Wq_h[256i x 64d] ----
    f32x4 acc1[4] = {};
    for (int ks = 0; ks < 8; ++ks) {
        bf16x8 a = *(const bf16x8*)&nrow[w * 16 + l15][ks * 32 + quad * 8];
        #pragma unroll
        for (int tt = 0; tt < 4; ++tt) {
            bf16x8 bfr = *(const bf16x8*)&wqT[tt * 16 + l15][ks * 32 + quad * 8];
            acc1[tt] = MFMA(a, bfr, acc1[tt]);
        }
    }
    #pragma unroll
    for (int tt = 0; tt < 4; ++tt)
        #pragma unroll
        for (int r = 0; r < 4; ++r)
            qb[w * 16 + quad * 4 + r][tt * 16 + l15] = (bf16_t)(acc1[tt][r] * 0.125f);
    __syncthreads();

    // ---- GEMM2: qt[64k x 256c] = q[64k x 64d] @ Wk_h^T[64d x 256c] ----
    f32x4 acc2[16] = {};
    for (int ks = 0; ks < 2; ++ks) {
        bf16x8 a = *(const bf16x8*)&qb[w * 16 + l15][ks * 32 + quad * 8];
        #pragma unroll
        for (int tt = 0; tt < 16; ++tt) {
            bf16x8 bfr = *(const bf16x8*)&wkT[tt * 16 + l15][ks * 32 + quad * 8];
            acc2[tt] = MFMA(a, bfr, acc2[tt]);
        }
    }
    size_t base = (size_t)(b * HH + h) * 64;
    #pragma unroll
    for (int tt = 0; tt < 16; ++tt)
        #pragma unroll
        for (int r = 0; r < 4; ++r)
            qt[(base + w * 16 + quad * 4 + r) * 256 + tt * 16 + l15] = (bf16_t)acc2[tt][r];
}

// ---------------------------------------------------------------------------
// Kernel 3: fused flash attention where K=V=hit_features.
// grid (B*H*NCc) blocks; each block: 64 q-rows (one head) x 2048 kv-rows.
// Wave w owns q-strip [w*16, w*16+16). Writes partial (ctx, m, l).
// ---------------------------------------------------------------------------
__global__ __launch_bounds__(256, 2) void k3_attn(
    const float* __restrict__ hit, const bf16_t* __restrict__ qt,
    float* __restrict__ ctxp, float* __restrict__ mp, float* __restrict__ lp)
{
    __shared__ alignas(16) bf16_t hs[64][264];     // hit subtile row-major
    __shared__ alignas(16) bf16_t hsT[256][72];    // transposed subtile
    __shared__ alignas(16) bf16_t pb[4][16][72];   // per-wave P round-trip

    const int bid = blockIdx.x;
    const int c  = bid & (NCc - 1);
    const int bh = bid / NCc;          // b*8 + h
    const int b  = bh >> 3;
    const int t  = threadIdx.x;
    const int w = t >> 6, lane = t & 63, l15 = lane & 15, quad = lane >> 4;

    // q~ fragments for this wave's 16 rows (A-operand, stays in registers)
    bf16x8 qf[8];
    {
        const bf16_t* qrow = qt + ((size_t)bh * 64 + w * 16 + l15) * 256;
        #pragma unroll
        for (int ks = 0; ks < 8; ++ks)
            qf[ks] = *(const bf16x8*)(qrow + ks * 32 + quad * 8);
    }

    f32x4 acc[16] = {};
    float mst[4] = {-1e30f, -1e30f, -1e30f, -1e30f};
    float lst[4] = {0.f, 0.f, 0.f, 0.f};

    const int dg = t & 31, rg = t >> 5;
    const int d0 = dg * 8, r0 = rg * 8;

    for (int s = 0; s < NCHUNK / 64; ++s) {
        const int n0 = c * NCHUNK + s * 64;
        __syncthreads();   // protect hs/hsT (readers of previous subtile done)
        // ---- stage 64x256 fp32 -> bf16 into hs and hsT ----
        for (int half = 0; half < 2; ++half) {
            float va[4][8];
            #pragma unroll
            for (int r = 0; r < 4; ++r) {
                const float4* src = (const float4*)
                    &hit[((size_t)b * Nn + n0 + r0 + half * 4 + r) * 256 + d0];
                float4 u0 = src[0], u1 = src[1];
                va[r][0] = u0.x; va[r][1] = u0.y; va[r][2] = u0.z; va[r][3] = u0.w;
                va[r][4] = u1.x; va[r][5] = u1.y; va[r][6] = u1.z; va[r][7] = u1.w;
            }
            #pragma unroll
            for (int r = 0; r < 4; ++r) {
                bf16x8 o;
                #pragma unroll
                for (int j = 0; j < 8; ++j) o[j] = (bf16_t)va[r][j];
                *(bf16x8*)&hs[r0 + half * 4 + r][d0] = o;
            }
            #pragma unroll
            for (int j = 0; j < 8; ++j) {
                bf16x4 o;
                #pragma unroll
                for (int r = 0; r < 4; ++r) o[r] = (bf16_t)va[r][j];
                *(bf16x4*)&hsT[d0 + j][r0 + half * 4] = o;
            }
        }
        __syncthreads();
        // ---- QK^T: S[16q x 64n] per wave ----
        f32x4 S[4] = {};
        for (int ks = 0; ks < 8; ++ks) {
            #pragma unroll
            for (int tt = 0; tt < 4; ++tt) {
                bf16x8 bfr = *(const bf16x8*)&hs[tt * 16 + l15][ks * 32 + quad * 8];
                S[tt] = MFMA(qf[ks], bfr, S[tt]);
            }
        }
        // ---- online softmax update (rows quad*4+r, reduce over 16 lanes) ----
        float al[4];
        #pragma unroll
        for (int r = 0; r < 4; ++r) {
            float tm = fmaxf(fmaxf(S[0][r], S[1][r]), fmaxf(S[2][r], S[3][r]));
            for (int m = 1; m < 16; m <<= 1) tm = fmaxf(tm, __shfl_xor(tm, m, 64));
            float mn = fmaxf(mst[r], tm);
            al[r] = __expf(mst[r] - mn);
            mst[r] = mn;
            float rs = 0.f;
            #pragma unroll
            for (int tt = 0; tt < 4; ++tt) {
                float e = __expf(S[tt][r] - mn);
                S[tt][r] = e;
                rs += e;
            }
            for (int m = 1; m < 16; m <<= 1) rs += __shfl_xor(rs, m, 64);
            lst[r] = lst[r] * al[r] + rs;
        }
        #pragma unroll
        for (int tt = 0; tt < 16; ++tt)
            #pragma unroll
            for (int r = 0; r < 4; ++r)
                acc[tt][r] *= al[r];
        // P (C-layout) -> LDS -> A-frag layout
        #pragma unroll
        for (int tt = 0; tt < 4; ++tt)
            #pragma unroll
            for (int r = 0; r < 4; ++r)
                pb[w][quad * 4 + r][tt * 16 + l15] = (bf16_t)S[tt][r];
        __syncthreads();   // also enforces LDS write->read ordering for pb
        // ---- PV: ctx[16q x 256d] += P[16q x 64n] @ hit_sub[64n x 256d] ----
        for (int j = 0; j < 2; ++j) {
            bf16x8 pa = *(const bf16x8*)&pb[w][l15][j * 32 + quad * 8];
            #pragma unroll
            for (int tt = 0; tt < 16; ++tt) {
                bf16x8 bfr = *(const bf16x8*)&hsT[tt * 16 + l15][j * 32 + quad * 8];
                acc[tt] = MFMA(pa, bfr, acc[tt]);
            }
        }
    }
    // ---- write partials ----
    const size_t obase = (size_t)bid * 64;   // (bh*NCc + c) * 64
    #pragma unroll
    for (int tt = 0; tt < 16; ++tt)
        #pragma unroll
        for (int r = 0; r < 4; ++r)
            ctxp[(obase + w * 16 + quad * 4 + r) * 256 + tt * 16 + l15] = acc[tt][r];
    if (l15 == 0) {
        #pragma unroll
        for (int r = 0; r < 4; ++r) {
            mp[obase + w * 16 + quad * 4 + r] = mst[r];
            lp[obase + w * 16 + quad * 4 + r] = lst[r];
        }
    }
}

// ---------------------------------------------------------------------------
// Kernel 4: combine partials + Wv + MLP + residual + LN2.
// grid (B * 8) blocks; block handles 8 slot rows (amortizes weight reads).
// ---------------------------------------------------------------------------
__global__ __launch_bounds__(256) void k4_out(
    const float* __restrict__ slots, const float* __restrict__ ctxp,
    const float* __restrict__ mp, const float* __restrict__ lp,
    const float* __restrict__ Wv, const float* __restrict__ W1,
    const float* __restrict__ b1v, const float* __restrict__ W2,
    const float* __restrict__ b2v, const float* __restrict__ g2,
    const float* __restrict__ bb2, float* __restrict__ out)
{
    __shared__ float ctx2[8][256][8];   // [h][c][r]
    __shared__ float attv2[512][8];     // [col][r]
    __shared__ float h1s[512][8];       // [col][r]
    __shared__ float ys[8][256];        // [r][col]

    const int b = blockIdx.x >> 3, kt = blockIdx.x & 7;
    const int t = threadIdx.x;

    // ---- phase A: softmax-combine partial ctx across chunks ----
    {
        const int h = t >> 5, dg = t & 31, d0 = dg * 8;
        const size_t bh = (size_t)b * 8 + h;
        for (int r = 0; r < 8; ++r) {
            int k = kt * 8 + r;
            float mv[8], lv[8], m = -1e30f;
            #pragma unroll
            for (int cc = 0; cc < 8; ++cc) {
                mv[cc] = mp[(bh * 8 + cc) * 64 + k];
                lv[cc] = lp[(bh * 8 + cc) * 64 + k];
                m = fmaxf(m, mv[cc]);
            }
            float ssum = 0.f, e[8];
            #pragma unroll
            for (int cc = 0; cc < 8; ++cc) { e[cc] = __expf(mv[cc] - m); ssum += lv[cc] * e[cc]; }
            float inv = 1.0f / ssum;
            float a8[8] = {};
            #pragma unroll
            for (int cc = 0; cc < 8; ++cc) {
                const float4* src = (const float4*)&ctxp[((bh * 8 + cc) * 64 + k) * 256 + d0];
                float4 u0 = src[0], u1 = src[1];
                a8[0] += e[cc] * u0.x; a8[1] += e[cc] * u0.y;
                a8[2] += e[cc] * u0.z; a8[3] += e[cc] * u0.w;
                a8[4] += e[cc] * u1.x; a8[5] += e[cc] * u1.y;
                a8[6] += e[cc] * u1.z; a8[7] += e[cc] * u1.w;
            }
            #pragma unroll
            for (int j = 0; j < 8; ++j) ctx2[h][d0 + j][r] = a8[j] * inv;
        }
    }
    __syncthreads();
    // ---- phase B: att_v[col] = ctx_h . Wv[:, col] ----
    {
        const int col0 = 2 * t, h = t >> 5;
        float acc0[8] = {}, acc1[8] = {};
        for (int cc = 0; cc < 256; ++cc) {
            float ua[8];
            *(float4*)&ua[0] = *(const float4*)&ctx2[h][cc][0];
            *(float4*)&ua[4] = *(const float4*)&ctx2[h][cc][4];
            float2 wv = *(const float2*)&Wv[(size_t)cc * 512 + col0];
            #pragma unroll
            for (int r = 0; r < 8; ++r) { acc0[r] += ua[r] * wv.x; acc1[r] += ua[r] * wv.y; }
        }
        #pragma unroll
        for (int r = 0; r < 8; ++r) { attv2[col0][r] = acc0[r]; attv2[col0 + 1][r] = acc1[r]; }
    }
    __syncthreads();
    // ---- phase C: h1 = relu(attv @ W1 + b1) ----
    {
        const int col0 = 2 * t;
        float acc0[8] = {}, acc1[8] = {};
        for (int j = 0; j < 512; ++j) {
            float ua[8];
            *(float4*)&ua[0] = *(const float4*)&attv2[j][0];
            *(float4*)&ua[4] = *(const float4*)&attv2[j][4];
            float2 wv = *(const float2*)&W1[(size_t)j * 512 + col0];
            #pragma unroll
            for (int r = 0; r < 8; ++r) { acc0[r] += ua[r] * wv.x; acc1[r] += ua[r] * wv.y; }
        }
        float bb0 = b1v[col0], bb1x = b1v[col0 + 1];
        #pragma unroll
        for (int r = 0; r < 8; ++r) {
            h1s[col0][r]     = fmaxf(acc0[r] + bb0, 0.f);
            h1s[col0 + 1][r] = fmaxf(acc1[r] + bb1x, 0.f);
        }
    }
    __syncthreads();
    // ---- phase D: y = h1 @ W2 + b2 + residual ----
    {
        float acc0[8] = {};
        for (int j = 0; j < 512; ++j) {
            float ua[8];
            *(float4*)&ua[0] = *(const float4*)&h1s[j][0];
            *(float4*)&ua[4] = *(const float4*)&h1s[j][4];
            float wv = W2[(size_t)j * 256 + t];
            #pragma unroll
            for (int r = 0; r < 8; ++r) acc0[r] += ua[r] * wv;
        }
        float bv = b2v[t];
        #pragma unroll
        for (int r = 0; r < 8; ++r) {
            int k = kt * 8 + r;
            ys[r][t] = slots[((size_t)b * 64 + k) * 256 + t] + acc0[r] + bv;
        }
    }
    __syncthreads();
    // ---- phase E: LN2 (wave-local per row) ----
    {
        const int w = t >> 6, lane = t & 63;
        float4 gv = *(const float4*)&g2[lane * 4];
        float4 bv = *(const float4*)&bb2[lane * 4];
        for (int rr = 0; rr < 2; ++rr) {
            int r = w + rr * 4;
            float4 x = *(const float4*)&ys[r][lane * 4];
            float s = x.x + x.y + x.z + x.w;
            for (int m = 1; m < 64; m <<= 1) s += __shfl_xor(s, m, 64);
            float mean = s * (1.0f / 256.0f);
            float dx = x.x - mean, dy = x.y - mean, dz = x.z - mean, dw = x.w - mean;
            float v2 = dx * dx + dy * dy + dz * dz + dw * dw;
            for (int m = 1; m < 64; m <<= 1) v2 += __shfl_xor(v2, m, 64);
            float rs = rsqrtf(v2 * (1.0f / 256.0f) + EPSf);
            int k = kt * 8 + r;
            float4 o;
            o.x = dx * rs * gv.x + bv.x;
            o.y = dy * rs * gv.y + bv.y;
            o.z = dz * rs * gv.z + bv.z;
            o.w = dw * rs * gv.w + bv.w;
            *(float4*)&out[((size_t)b * 64 + k) * 256 + lane * 4] = o;
        }
    }
}

// ---------------------------------------------------------------------------
extern "C" void kernel_launch(void* const* d_in, const int* in_sizes, int n_in,
                              void* d_out, int out_size, void* d_ws, size_t ws_size,
                              hipStream_t stream) {
    (void)in_sizes; (void)n_in; (void)out_size; (void)ws_size;
    const float* slots = (const float*)d_in[0];
    const float* hit   = (const float*)d_in[1];
    const float* g1    = (const float*)d_in[2];
    const float* bb1   = (const float*)d_in[3];
    const float* Wq    = (const float*)d_in[4];
    const float* Wk    = (const float*)d_in[5];
    const float* Wv    = (const float*)d_in[6];
    const float* W1    = (const float*)d_in[7];
    const float* b1v   = (const float*)d_in[8];
    const float* W2    = (const float*)d_in[9];
    const float* b2v   = (const float*)d_in[10];
    const float* g2    = (const float*)d_in[11];
    const float* bb2   = (const float*)d_in[12];
    float* out = (float*)d_out;

    // workspace layout (~34.3 MB total)
    char* wsp = (char*)d_ws;
    bf16_t* qt  = (bf16_t*)wsp;                                   // 2 MB
    float* ctxp = (float*)(wsp + (size_t)2097152);                // 33.55 MB
    float* mp   = (float*)(wsp + (size_t)2097152 + 33554432);     // 128 KB
    float* lp   = mp + (size_t)Bb * HH * NCc * 64;                // 128 KB

    hipLaunchKernelGGL(k1_qt, dim3(Bb * HH), dim3(256), 0, stream,
                       slots, g1, bb1, Wq, Wk, qt);
    hipLaunchKernelGGL(k3_attn, dim3(Bb * HH * NCc), dim3(256), 0, stream,
                       hit, qt, ctxp, mp, lp);
    hipLaunchKernelGGL(k4_out, dim3(Bb * 8), dim3(256), 0, stream,
                       slots, ctxp, mp, lp, Wv, W1, b1v, W2, b2v, g2, bb2, out);
}